// Round 11
// baseline (284.002 us; speedup 1.0000x reference)
//
#include <hip/hip_runtime.h>
#include <math.h>

constexpr int V = 128;   // vocab (fixed for this instance)

// ---- DPP wave-wide shifts (VALU, no LDS pipe, no lgkm wait) ----
__device__ __forceinline__ double dpp_shr1_f64(double x) {
    int lo = __builtin_amdgcn_update_dpp(0, __double2loint(x), 0x138, 0xf, 0xf, false);
    int hi = __builtin_amdgcn_update_dpp(0, __double2hiint(x), 0x138, 0xf, 0xf, false);
    return __hiloint2double(hi, lo);
}
__device__ __forceinline__ double dpp_shl1_f64(double x) {
    int lo = __builtin_amdgcn_update_dpp(0, __double2loint(x), 0x130, 0xf, 0xf, false);
    int hi = __builtin_amdgcn_update_dpp(0, __double2hiint(x), 0x130, 0xf, 0xf, false);
    return __hiloint2double(hi, lo);
}

__device__ __forceinline__ unsigned f32_to_bf16_rne(float f) {
    unsigned u = __float_as_uint(f);
    return (u + 0x7fffu + ((u >> 16) & 1u)) >> 16;
}

// ======================= PATH A ============================================
// MEASURED HISTORY:
// r9:  producer->consumer spin across the GRID thrashes L2 (flag polling).
// r10-r15: f32 state loses to f64 regardless of spills/rescale depth.
// r16: depth-32 f32 ring = register cliff, regression.
// r17: f64 depth-16 + plumbing: scan 81us. r18: bf16 g, FETCH halved,
//   depth 32: scan 81.4 (NO change). r19: consumer fed from LDS by a
//   producer wave, ZERO VMEM in consumer loop: scan 81.9 (NO change).
//   => 190cyc/step is structural (issue ~100 + dep/hazard stall ~90),
//   invariant to state dtype, depth, traffic, and memory path. Wave
//   packing can't help (2x100 issue = 200 > 190). Scan is at its floor.
// r20: attack the OTHER ~86us (dur ~= scan + 86 for 10 rounds): FULL
//   FUSION into one kernel. wave1 computes g rows directly from pred
//   (shfl-gather; no LDS staging bubbles), wave2 computes z row-sums,
//   wave0 = r19's verified consumer. Eliminates: prelude kernel+launch,
//   g16 write+re-read (16+13.5 MB HBM), z array. Intra-block structure
//   is r19-verified; inter-block rendezvous pattern unchanged.
__global__ __launch_bounds__(192, 1) void ctc_fused_bi(
    const float* __restrict__ pred,
    const int*   __restrict__ pred_len,
    const int*   __restrict__ gt,
    const int*   __restrict__ gt_len,
    double*      __restrict__ fwdv,   // [B,520]
    double*      __restrict__ bwdv,   // [B,520]
    int*         __restrict__ Kf,     // [B]
    int*         __restrict__ Kb,     // [B]
    double*      __restrict__ zpart,  // [2B] per-direction zs partials
    int* done, int* gdone, float* lossb,
    float* __restrict__ out,
    int T, int S, int B)
{
    const int blk  = blockIdx.x;
    const int b    = blk >> 1;
    const int dir  = blk & 1;
    const int wv   = threadIdx.x >> 6;   // 0=consumer 1=g-producer 2=z-producer
    const int lane = threadIdx.x & 63;
    const int len  = pred_len[b];     // host guards T>=128 -> len>=64
    const int tl   = gt_len[b];
    const int L    = 2 * tl + 1;
    const int m    = (len + 1) >> 1;  // fwd rows (>=32); nb = len-m >= 32

    __shared__ uint2  ring[2][32][64];   // 32 KB double-buffered g chunks
    __shared__ double zsh;               // wv2 -> wv0 handoff

    int4 la = *(const int4*)(gt + b * S + 4 * lane);
    int law_up = __shfl_up(la.w, 1, 64);     // init-time only: DS ok here
    int lax_dn = __shfl_down(la.x, 1, 64);
    const double sk0 = (lane > 0 && la.x != law_up) ? 1.0 : 0.0; // skip[8i+1]
    const double sk1 = (la.y != la.x) ? 1.0 : 0.0;               // skip[8i+3]
    const double sk2 = (la.z != la.y) ? 1.0 : 0.0;               // skip[8i+5]
    const double sk3 = (la.w != la.z) ? 1.0 : 0.0;               // skip[8i+7]
    const double sk4 = (lax_dn != la.w) ? 1.0 : 0.0;             // skip[8i+9]

    const float2* rowp = (const float2*)(pred + (size_t)b * T * V);

    double u[9];
    int    K  = 0;
    double zs = 0.0;

    auto RESCALE = [&]() {
        double mx = u[0];
        #pragma unroll
        for (int j = 1; j < 9; ++j) mx = fmax(mx, u[j]);
        #pragma unroll
        for (int off = 32; off >= 1; off >>= 1)
            mx = fmax(mx, __shfl_xor(mx, off, 64));
        int k = ((__double2hiint(mx) >> 20) & 0x7ff) - 1023;
        #pragma unroll
        for (int j = 0; j < 9; ++j) u[j] = ldexp(u[j], -k);  // exact
        K += k;
    };

    auto FSTEP_Q = [&](uint2 q) {
        double um1 = dpp_shr1_f64(u[7]);          // lane0 -> 0 (exact)
        double gx = (double)__uint_as_float(q.x << 16);
        double gy = (double)__uint_as_float(q.x & 0xffff0000u);
        double gz = (double)__uint_as_float(q.y << 16);
        double gw = (double)__uint_as_float(q.y & 0xffff0000u);
        u[8] = u[8] + u[7];
        u[7] = (fma(sk3, u[5], u[6]) + u[7]) * gw;
        u[6] = u[6] + u[5];
        u[5] = (fma(sk2, u[3], u[4]) + u[5]) * gz;
        u[4] = u[4] + u[3];
        u[3] = (fma(sk1, u[1], u[2]) + u[3]) * gy;
        u[2] = u[2] + u[1];
        u[1] = (fma(sk0, um1, u[0]) + u[1]) * gx;
        u[0] = u[0] + um1;
    };

    auto BSTEP_Q = [&](uint2 q) {
        double d0 = dpp_shl1_f64(u[0]);           // slot 8i+8 (pre-step)
        if (lane == 63) d0 = u[8];
        double gx = (double)__uint_as_float(q.x << 16);
        double gy = (double)__uint_as_float(q.x & 0xffff0000u);
        double gz = (double)__uint_as_float(q.y << 16);
        double gw = (double)__uint_as_float(q.y & 0xffff0000u);
        double p1 = gx * u[1], p3 = gy * u[3];
        double p5 = gz * u[5], p7 = gw * u[7];
        double dp = dpp_shl1_f64(p1);             // lane63 -> 0
        u[0] = u[0] + p1;
        u[1] = fma(sk1, p3, u[2]) + p1;
        u[2] = u[2] + p3;
        u[3] = fma(sk2, p5, u[4]) + p3;
        u[4] = u[4] + p5;
        u[5] = fma(sk3, p7, u[6]) + p5;
        u[6] = u[6] + p7;
        u[7] = fma(sk4, dp, d0) + p7;
    };

    // wv1: compute g for one row held in v, write to ring[buf][idx]
    auto GROW = [&](float2 v, int buf, int idx) {
        float x0 = __shfl(v.x, 0, 64);
        float a0 = __shfl(v.x, la.x >> 1, 64), b0 = __shfl(v.y, la.x >> 1, 64);
        float a1 = __shfl(v.x, la.y >> 1, 64), b1 = __shfl(v.y, la.y >> 1, 64);
        float a2 = __shfl(v.x, la.z >> 1, 64), b2 = __shfl(v.y, la.z >> 1, 64);
        float a3 = __shfl(v.x, la.w >> 1, 64), b3 = __shfl(v.y, la.w >> 1, 64);
        float g0 = (la.x & 1) ? b0 : a0;
        float g1 = (la.y & 1) ? b1 : a1;
        float g2 = (la.z & 1) ? b2 : a2;
        float g3 = (la.w & 1) ? b3 : a3;
        float o0 = (4 * lane + 0 < tl) ? __expf(g0 - x0) : 0.f;
        float o1 = (4 * lane + 1 < tl) ? __expf(g1 - x0) : 0.f;
        float o2 = (4 * lane + 2 < tl) ? __expf(g2 - x0) : 0.f;
        float o3 = (4 * lane + 3 < tl) ? __expf(g3 - x0) : 0.f;
        uint2 w;
        w.x = f32_to_bf16_rne(o0) | (f32_to_bf16_rne(o1) << 16);
        w.y = f32_to_bf16_rne(o2) | (f32_to_bf16_rne(o3) << 16);
        ring[buf][idx][lane] = w;
    };

    // wv2: z_t - x0_t for one row in v; accumulate if keep
    auto ZROW = [&](float2 v, bool keep) {
        float x0 = __shfl(v.x, 0, 64);
        float s = __expf(v.x - x0) + __expf(v.y - x0);
        #pragma unroll
        for (int off = 32; off >= 1; off >>= 1) s += __shfl_xor(s, off, 64);
        if (keep) zs += (double)__logf(s);
    };

    if (dir == 0) {
        // ---------------- forward: rows 0..m-1 (row 0 = init) -------------
        #pragma unroll
        for (int j = 0; j < 9; ++j) u[j] = 0.0;
        const int nrows = m;
        const int nch = (nrows + 31) >> 5;
        for (int it = 0; it <= nch; ++it) {
            if (wv == 1 && it < nch) {       // produce chunk it
                int base = it << 5, buf = it & 1;
                #pragma unroll
                for (int h = 0; h < 2; ++h) {
                    float2 vr[16];
                    #pragma unroll
                    for (int j = 0; j < 16; ++j)
                        vr[j] = rowp[(size_t)(base + h * 16 + j) * 64 + lane];
                    #pragma unroll
                    for (int j = 0; j < 16; ++j) GROW(vr[j], buf, h * 16 + j);
                }
            }
            if (wv == 2 && it < nch) {       // z for chunk it's rows
                int base = it << 5;
                #pragma unroll
                for (int h = 0; h < 2; ++h) {
                    float2 vr[16];
                    #pragma unroll
                    for (int j = 0; j < 16; ++j)
                        vr[j] = rowp[(size_t)(base + h * 16 + j) * 64 + lane];
                    #pragma unroll
                    for (int j = 0; j < 16; ++j)
                        ZROW(vr[j], base + h * 16 + j < nrows);
                }
            }
            if (wv == 0 && it >= 1) {        // consume chunk it-1
                int c = it - 1;
                int buf = c & 1;
                uint2 rr[4];
                #pragma unroll
                for (int j = 0; j < 4; ++j) rr[j] = ring[buf][j][lane];
                if (c == 0) {                // init row + 31 steps
                    if (lane == 0) {
                        u[0] = 1.0;
                        u[1] = (double)__uint_as_float(rr[0].x << 16);
                    }
                    rr[0] = ring[buf][4][lane];
                    #pragma unroll
                    for (int i = 1; i < 32; ++i) {
                        uint2 q = rr[i & 3];
                        if (i + 4 < 32) rr[i & 3] = ring[buf][i + 4][lane];
                        FSTEP_Q(q);
                    }
                } else if (((c + 1) << 5) <= nrows) {   // full chunk
                    #pragma unroll
                    for (int i = 0; i < 32; ++i) {
                        uint2 q = rr[i & 3];
                        if (i + 4 < 32) rr[i & 3] = ring[buf][i + 4][lane];
                        FSTEP_Q(q);
                    }
                } else {                                 // tail chunk
                    int rem = nrows - (c << 5);
                    #pragma unroll
                    for (int i = 0; i < 32; ++i) {
                        if (i < rem) {
                            uint2 q = rr[i & 3];
                            if (i + 4 < 32) rr[i & 3] = ring[buf][i + 4][lane];
                            FSTEP_Q(q);
                        }
                    }
                }
                if (c & 1) RESCALE();        // <=64-step spacing
            }
            __syncthreads();
        }
        if (wv == 0) {
            RESCALE();                       // normalize before junction
            double* outv = fwdv + (size_t)b * 520;
            #pragma unroll
            for (int j = 0; j < 8; ++j) outv[8 * lane + j] = u[j];
            if (lane == 63) outv[512] = u[8];
            if (lane == 0)  Kf[b] = K;
        }
    } else {
        // ---------------- backward: k=0..nb-1, row = len-1-k --------------
        const int nb = len - m;              // >= 32
        #pragma unroll
        for (int j = 0; j < 8; ++j) {
            int s = 8 * lane + j;
            u[j] = (s == 2 * tl || s == 2 * tl - 1) ? 1.0 : 0.0;
        }
        u[8] = (lane == 63 && L == 513) ? 1.0 : 0.0;   // slot 512 (lane 63)
        const int nrows = nb;
        const int nch = (nrows + 31) >> 5;
        for (int it = 0; it <= nch; ++it) {
            if (wv == 1 && it < nch) {
                int base = it << 5, buf = it & 1;
                #pragma unroll
                for (int h = 0; h < 2; ++h) {
                    float2 vr[16];
                    #pragma unroll
                    for (int j = 0; j < 16; ++j)
                        vr[j] = rowp[(size_t)(len - 1 - (base + h * 16 + j)) * 64 + lane];
                    #pragma unroll
                    for (int j = 0; j < 16; ++j) GROW(vr[j], buf, h * 16 + j);
                }
            }
            if (wv == 2 && it < nch) {
                int base = it << 5;
                #pragma unroll
                for (int h = 0; h < 2; ++h) {
                    float2 vr[16];
                    #pragma unroll
                    for (int j = 0; j < 16; ++j)
                        vr[j] = rowp[(size_t)(len - 1 - (base + h * 16 + j)) * 64 + lane];
                    #pragma unroll
                    for (int j = 0; j < 16; ++j)
                        ZROW(vr[j], base + h * 16 + j < nrows);
                }
            }
            if (wv == 0 && it >= 1) {
                int c = it - 1;
                int buf = c & 1;
                uint2 rr[4];
                #pragma unroll
                for (int j = 0; j < 4; ++j) rr[j] = ring[buf][j][lane];
                if (((c + 1) << 5) <= nrows) {    // full chunk
                    #pragma unroll
                    for (int i = 0; i < 32; ++i) {
                        uint2 q = rr[i & 3];
                        if (i + 4 < 32) rr[i & 3] = ring[buf][i + 4][lane];
                        BSTEP_Q(q);
                    }
                } else {                          // tail chunk
                    int rem = nrows - (c << 5);
                    #pragma unroll
                    for (int i = 0; i < 32; ++i) {
                        if (i < rem) {
                            uint2 q = rr[i & 3];
                            if (i + 4 < 32) rr[i & 3] = ring[buf][i + 4][lane];
                            BSTEP_Q(q);
                        }
                    }
                }
                if (c & 1) RESCALE();
            }
            __syncthreads();
        }
        if (wv == 0) {
            RESCALE();
            double* outv = bwdv + (size_t)b * 520;
            #pragma unroll
            for (int j = 0; j < 8; ++j) outv[8 * lane + j] = u[j];
            if (lane == 63) outv[512] = u[8];
            if (lane == 0)  Kb[b] = K;
        }
    }

    // -------- zs handoff (wv2 -> wv0), then inter-block rendezvous --------
    if (wv == 2 && lane == 0) zsh = zs;
    __syncthreads();
    if (wv != 0) return;                 // producers done (no barriers left)

    if (lane == 0) zpart[blk] = zsh;     // publish this half's zs
    __threadfence();
    int prev = 0;
    if (lane == 0)
        prev = __hip_atomic_fetch_add(&done[b], 1, __ATOMIC_ACQ_REL,
                                      __HIP_MEMORY_SCOPE_AGENT);
    prev = __shfl(prev, 0, 64);
    if (prev == 0) return;               // first arriver: exit immediately
    __threadfence();                     // acquire the other block's stores

    const double* f = fwdv + (size_t)b * 520;
    const double* w = bwdv + (size_t)b * 520;
    double c = 0.0;
    #pragma unroll
    for (int j = 0; j < 8; ++j)
        c = fma(f[8 * lane + j], w[8 * lane + j], c);
    if (lane == 63) c = fma(f[512], w[512], c);
    #pragma unroll
    for (int off = 32; off >= 1; off >>= 1) c += __shfl_xor(c, off, 64);

    if (lane == 0) {
        double zstot = zpart[2 * b] + zpart[2 * b + 1];
        double logp = log(c)
                    + (double)(Kf[b] + Kb[b]) * 0.6931471805599453 - zstot;
        double loss = -logp;
        if (!(loss < 1e10)) loss = 0.0;   // zero_infinity (+inf / NaN)
        if (loss < 0.0)     loss = 0.0;   // CTC loss >= 0: circuit breaker
        lossb[b] = (float)(loss / (double)tl);
        __threadfence();
        int pg = __hip_atomic_fetch_add(gdone, 1, __ATOMIC_ACQ_REL,
                                        __HIP_MEMORY_SCOPE_AGENT);
        if (pg == B - 1) {                // last batch: deterministic mean
            __threadfence();
            float ssum = 0.0f;
            for (int i = 0; i < B; ++i) ssum += lossb[i];
            out[0] = ssum / (float)B;
        }
    }
}

// ======================= PATH B (fallback: proven round-3) ==================
constexpr int SPL  = 9;
constexpr int RING = 32;

__global__ void ctc_reduce_kernel(const float* __restrict__ ls,
                                  float* __restrict__ out, int B)
{
    if (blockIdx.x == 0 && threadIdx.x == 0) {
        float s = 0.0f;
        for (int i = 0; i < B; ++i) s += ls[i];
        out[0] = s / (float)B;
    }
}

__global__ __launch_bounds__(256) void softmax_z_kernel(
    const float* __restrict__ pred, float* __restrict__ z, int nrows)
{
    int w    = blockIdx.x * 4 + (threadIdx.x >> 6);
    int lane = threadIdx.x & 63;
    if (w >= nrows) return;
    const float2* p = (const float2*)pred;
    float2 v = p[(size_t)w * 64 + lane];
    float s = __expf(v.x) + __expf(v.y);
    #pragma unroll
    for (int off = 32; off >= 1; off >>= 1) s += __shfl_xor(s, off, 64);
    if (lane == 0) z[w] = __logf(s);
}

__device__ __forceinline__ void ctc_step_fb(
    const float* __restrict__ rowbase, const int* __restrict__ goff,
    const double* __restrict__ skd, double (&u)[SPL], int lane)
{
    float gf[SPL];
    #pragma unroll
    for (int j = 0; j < SPL; ++j)
        gf[j] = *(const float*)((const char*)rowbase + goff[j]);
    double um1 = __shfl_up(u[8], 1, 64);
    double um2 = __shfl_up(u[7], 1, 64);
    if (lane == 0) { um1 = 0.0; um2 = 0.0; }
    #pragma unroll
    for (int jj = 0; jj < SPL; ++jj) {
        int j = SPL - 1 - jj;
        double a2 = (j >= 1) ? u[j - 1] : um1;
        double a3 = (j >= 2) ? u[j - 2] : ((j == 1) ? um1 : um2);
        double t  = fma(skd[j], a3, a2) + u[j];
        u[j] = t * (double)gf[j];
    }
}

__device__ __forceinline__ void ctc_rescale_fb(double (&u)[SPL], int& K)
{
    double m = u[0];
    #pragma unroll
    for (int j = 1; j < SPL; ++j) m = fmax(m, u[j]);
    #pragma unroll
    for (int off = 32; off >= 1; off >>= 1) m = fmax(m, __shfl_xor(m, off, 64));
    if (m > 0.0) {
        int e = (__double2hiint(m) >> 20) & 0x7ff;
        int k = e - 1023;
        #pragma unroll
        for (int j = 0; j < SPL; ++j) u[j] = ldexp(u[j], -k);
        K += k;
    }
}

__global__ __launch_bounds__(64) void ctc_scan_kernel(
    const float* __restrict__ pred, const int* __restrict__ pred_len,
    const int* __restrict__ gt, const int* __restrict__ gt_len,
    const float* __restrict__ z, float* __restrict__ loss_out, int T, int S)
{
    const int b    = blockIdx.x;
    const int lane = threadIdx.x;
    const int len  = pred_len[b];
    const int tl   = gt_len[b];
    const int L    = 2 * tl + 1;

    __shared__ float ring[RING][V];
    __shared__ int   gts[512];

    for (int i = lane; i < S; i += 64) gts[i] = gt[b * S + i];
    __syncthreads();

    int    goff[SPL];
    double skd[SPL];
    #pragma unroll
    for (int j = 0; j < SPL; ++j) {
        int s = SPL * lane + j;
        int e = 0, ep = 0;
        if (s < L && (s & 1)) e = gts[s >> 1];
        if (s >= 2 && s < L && (s & 1)) ep = gts[(s - 2) >> 1];
        goff[j] = e * 4;
        skd[j]  = (s >= 2 && s < L && e != 0 && e != ep) ? 1.0 : 0.0;
    }

    const float2* rowp = (const float2*)(pred + (size_t)b * T * V);
    float2 raw[16];

    #pragma unroll
    for (int i = 0; i < 16; ++i) raw[i] = rowp[(size_t)i * 64 + lane];
    #pragma unroll
    for (int i = 0; i < 16; ++i) {
        float2 w; w.x = __expf(raw[i].x); w.y = __expf(raw[i].y);
        *(float2*)&ring[i][2 * lane] = w;
    }
    #pragma unroll
    for (int i = 0; i < 16; ++i) raw[i] = rowp[(size_t)(16 + i) * 64 + lane];
    #pragma unroll
    for (int i = 0; i < 16; ++i) {
        float2 w; w.x = __expf(raw[i].x); w.y = __expf(raw[i].y);
        *(float2*)&ring[16 + i][2 * lane] = w;
    }
    #pragma unroll
    for (int i = 0; i < 16; ++i) {
        int r = 32 + i; if (r > T - 1) r = T - 1;
        raw[i] = rowp[(size_t)r * 64 + lane];
    }

    double u[SPL];
    #pragma unroll
    for (int j = 0; j < SPL; ++j) {
        int s = SPL * lane + j;
        float w0 = *(const float*)((const char*)&ring[0][0] + goff[j]);
        u[j] = (s < 2) ? (double)w0 : 0.0;
    }
    int K = 0;

    for (int t = 1; t < 16 && t < len; ++t)
        ctc_step_fb(&ring[t & (RING - 1)][0], goff, skd, u, lane);
    ctc_rescale_fb(u, K);

    int tb = 16;
    for (; tb + 16 <= len; tb += 16) {
        #pragma unroll
        for (int i = 0; i < 16; ++i) {
            float2 w; w.x = __expf(raw[i].x); w.y = __expf(raw[i].y);
            *(float2*)&ring[(tb + 16 + i) & (RING - 1)][2 * lane] = w;
        }
        #pragma unroll
        for (int i = 0; i < 16; ++i) {
            int r = tb + 32 + i; if (r > T - 1) r = T - 1;
            raw[i] = rowp[(size_t)r * 64 + lane];
        }
        #pragma unroll
        for (int i = 0; i < 16; ++i)
            ctc_step_fb(&ring[(tb + i) & (RING - 1)][0], goff, skd, u, lane);
        ctc_rescale_fb(u, K);
    }

    for (int t = tb; t < len; ++t)
        ctc_step_fb(&ring[t & (RING - 1)][0], goff, skd, u, lane);

    double contrib = 0.0;
    #pragma unroll
    for (int j = 0; j < SPL; ++j) {
        int s = SPL * lane + j;
        if (s == L - 1 || s == L - 2) contrib += u[j];
    }
    #pragma unroll
    for (int off = 32; off >= 1; off >>= 1)
        contrib += __shfl_xor(contrib, off, 64);

    double zsum = 0.0;
    for (int t = lane; t < len; t += 64) zsum += (double)z[b * T + t];
    #pragma unroll
    for (int off = 32; off >= 1; off >>= 1)
        zsum += __shfl_xor(zsum, off, 64);

    if (lane == 0) {
        double lg    = log(contrib);
        double alpha = lg + (double)K * 0.6931471805599453 - zsum;
        double loss  = -alpha;
        if (!(loss < 1e10)) loss = 0.0;
        loss_out[b] = (float)(loss / (double)tl);
    }
}

// ======================= host =======================
extern "C" void kernel_launch(void* const* d_in, const int* in_sizes, int n_in,
                              void* d_out, int out_size, void* d_ws, size_t ws_size,
                              hipStream_t stream) {
    const float* pred = (const float*)d_in[0];   // [B, T, V] fp32
    const int*   plen = (const int*)d_in[1];     // [B]
    const int*   gts  = (const int*)d_in[2];     // [B, S]
    const int*   glen = (const int*)d_in[3];     // [B]

    const int B = in_sizes[1];
    const int S = in_sizes[2] / B;
    const int T = in_sizes[0] / (B * V);
    const size_t BT = (size_t)B * T;

    float* out = (float*)d_out;
    char*  ws  = (char*)d_ws;

    // fast-path workspace layout (tiny now: no g/z intermediates)
    size_t off_fl = 0;                               // done[64]@0 gdone@256 lossb@512
    size_t off_zp = 1024;                            // zpart: 2B doubles
    size_t off_fw = 2048;
    size_t off_bw = off_fw + (size_t)B * 520 * 8;
    size_t off_kf = off_bw + (size_t)B * 520 * 8;
    size_t off_kb = off_kf + (size_t)B * 4;
    size_t need   = off_kb + (size_t)B * 4;

    // T >= 128 (=> len >= 64 => m,nb >= 32) required by 32-row chunking
    bool fast_ok = (ws_size >= need) && (S == 256) &&
                   (T >= 128) && (B >= 1) && (B <= 64);

    if (fast_ok) {
        int*    flags = (int*)(ws + off_fl);
        int*    done  = flags;
        int*    gdone = flags + 64;
        float*  lossb = (float*)(ws + off_fl + 512);
        double* zp    = (double*)(ws + off_zp);
        double* fw    = (double*)(ws + off_fw);
        double* bw    = (double*)(ws + off_bw);
        int*    kf    = (int*)(ws + off_kf);
        int*    kb    = (int*)(ws + off_kb);

        hipMemsetAsync(ws + off_fl, 0, 512, stream);   // done + gdone
        ctc_fused_bi<<<2 * B, 192, 0, stream>>>(pred, plen, gts, glen,
                                                fw, bw, kf, kb, zp,
                                                done, gdone, lossb, out,
                                                T, S, B);
    } else {
        float* zbuf = (float*)ws;                 // B*T
        float* lb   = zbuf + BT;                  // B
        int nrows = B * T;
        softmax_z_kernel<<<(nrows + 3) / 4, 256, 0, stream>>>(pred, zbuf, nrows);
        ctc_scan_kernel<<<B, 64, 0, stream>>>(pred, plen, gts, glen, zbuf, lb, T, S);
        ctc_reduce_kernel<<<1, 64, 0, stream>>>(lb, out, B);
    }
}

// Round 12
// 277.644 us; speedup vs baseline: 1.0229x; 1.0229x over previous
//
#include <hip/hip_runtime.h>
#include <math.h>

constexpr int V = 128;   // vocab (fixed for this instance)

// ---- DPP wave-wide shifts (VALU, no LDS pipe, no lgkm wait) ----
__device__ __forceinline__ double dpp_shr1_f64(double x) {
    int lo = __builtin_amdgcn_update_dpp(0, __double2loint(x), 0x138, 0xf, 0xf, false);
    int hi = __builtin_amdgcn_update_dpp(0, __double2hiint(x), 0x138, 0xf, 0xf, false);
    return __hiloint2double(hi, lo);
}
__device__ __forceinline__ double dpp_shl1_f64(double x) {
    int lo = __builtin_amdgcn_update_dpp(0, __double2loint(x), 0x130, 0xf, 0xf, false);
    int hi = __builtin_amdgcn_update_dpp(0, __double2hiint(x), 0x130, 0xf, 0xf, false);
    return __hiloint2double(hi, lo);
}

__device__ __forceinline__ unsigned f32_to_bf16_rne(float f) {
    unsigned u = __float_as_uint(f);
    return (u + 0x7fffu + ((u >> 16) & 1u)) >> 16;
}

// ======================= PATH A ============================================
// MEASURED HISTORY:
// r9:  cross-GRID producer/consumer spin thrashes L2 (flag polling).
// r10-r15: f32 state loses to f64 regardless of spills/rescale depth.
// r16: depth-32 f32 ring = register cliff. r17: f64 depth-16 + plumbing:
//   scan 81us, total 166. r18: bf16 g (FETCH halved, depth 32): scan 81.4
//   (no change). r19: consumer fed from LDS by producer wave, zero VMEM in
//   consumer loop: 81.9 (no change) => 190cyc/step is structural.
// r20: FULL FUSION, 3 waves. Correct but 222us: the shfl-gather
//   (ds_bpermute, random labels) cost ~800K bank-conflict cycles on ONE
//   producer wave -> producer chunk > consumer chunk -> barrier-gated 2.7x.
//   BUT: total-dispatch overhead = 62us fused vs 85us two-kernel -> fusion
//   itself saves ~23us of launch+prelude if the producer is hidden again.
// r21: split the gather across TWO waves (wv1 rows 0-15, wv3 rows 16-31 of
//   each chunk) -> ~2.5k cyc/chunk per gather wave < consumer's 6.1k ->
//   gather back off the critical path (r19-verified overlap). Consumer,
//   ring, rescale cadence, rendezvous: byte-identical to passing r20.
__global__ __launch_bounds__(256, 1) void ctc_fused_bi(
    const float* __restrict__ pred,
    const int*   __restrict__ pred_len,
    const int*   __restrict__ gt,
    const int*   __restrict__ gt_len,
    double*      __restrict__ fwdv,   // [B,520]
    double*      __restrict__ bwdv,   // [B,520]
    int*         __restrict__ Kf,     // [B]
    int*         __restrict__ Kb,     // [B]
    double*      __restrict__ zpart,  // [2B] per-direction zs partials
    int* done, int* gdone, float* lossb,
    float* __restrict__ out,
    int T, int S, int B)
{
    const int blk  = blockIdx.x;
    const int b    = blk >> 1;
    const int dir  = blk & 1;
    const int wv   = threadIdx.x >> 6;   // 0=consumer 1,3=g-gather 2=z
    const int lane = threadIdx.x & 63;
    const int len  = pred_len[b];     // host guards T>=128 -> len>=64
    const int tl   = gt_len[b];
    const int L    = 2 * tl + 1;
    const int m    = (len + 1) >> 1;  // fwd rows (>=32); nb = len-m >= 32

    __shared__ uint2  ring[2][32][64];   // 32 KB double-buffered g chunks
    __shared__ double zsh;               // wv2 -> wv0 handoff

    int4 la = *(const int4*)(gt + b * S + 4 * lane);
    int law_up = __shfl_up(la.w, 1, 64);     // init-time only: DS ok here
    int lax_dn = __shfl_down(la.x, 1, 64);
    const double sk0 = (lane > 0 && la.x != law_up) ? 1.0 : 0.0; // skip[8i+1]
    const double sk1 = (la.y != la.x) ? 1.0 : 0.0;               // skip[8i+3]
    const double sk2 = (la.z != la.y) ? 1.0 : 0.0;               // skip[8i+5]
    const double sk3 = (la.w != la.z) ? 1.0 : 0.0;               // skip[8i+7]
    const double sk4 = (lax_dn != la.w) ? 1.0 : 0.0;             // skip[8i+9]

    const float2* rowp = (const float2*)(pred + (size_t)b * T * V);

    double u[9];
    int    K  = 0;
    double zs = 0.0;

    auto RESCALE = [&]() {
        double mx = u[0];
        #pragma unroll
        for (int j = 1; j < 9; ++j) mx = fmax(mx, u[j]);
        #pragma unroll
        for (int off = 32; off >= 1; off >>= 1)
            mx = fmax(mx, __shfl_xor(mx, off, 64));
        int k = ((__double2hiint(mx) >> 20) & 0x7ff) - 1023;
        #pragma unroll
        for (int j = 0; j < 9; ++j) u[j] = ldexp(u[j], -k);  // exact
        K += k;
    };

    auto FSTEP_Q = [&](uint2 q) {
        double um1 = dpp_shr1_f64(u[7]);          // lane0 -> 0 (exact)
        double gx = (double)__uint_as_float(q.x << 16);
        double gy = (double)__uint_as_float(q.x & 0xffff0000u);
        double gz = (double)__uint_as_float(q.y << 16);
        double gw = (double)__uint_as_float(q.y & 0xffff0000u);
        u[8] = u[8] + u[7];
        u[7] = (fma(sk3, u[5], u[6]) + u[7]) * gw;
        u[6] = u[6] + u[5];
        u[5] = (fma(sk2, u[3], u[4]) + u[5]) * gz;
        u[4] = u[4] + u[3];
        u[3] = (fma(sk1, u[1], u[2]) + u[3]) * gy;
        u[2] = u[2] + u[1];
        u[1] = (fma(sk0, um1, u[0]) + u[1]) * gx;
        u[0] = u[0] + um1;
    };

    auto BSTEP_Q = [&](uint2 q) {
        double d0 = dpp_shl1_f64(u[0]);           // slot 8i+8 (pre-step)
        if (lane == 63) d0 = u[8];
        double gx = (double)__uint_as_float(q.x << 16);
        double gy = (double)__uint_as_float(q.x & 0xffff0000u);
        double gz = (double)__uint_as_float(q.y << 16);
        double gw = (double)__uint_as_float(q.y & 0xffff0000u);
        double p1 = gx * u[1], p3 = gy * u[3];
        double p5 = gz * u[5], p7 = gw * u[7];
        double dp = dpp_shl1_f64(p1);             // lane63 -> 0
        u[0] = u[0] + p1;
        u[1] = fma(sk1, p3, u[2]) + p1;
        u[2] = u[2] + p3;
        u[3] = fma(sk2, p5, u[4]) + p3;
        u[4] = u[4] + p5;
        u[5] = fma(sk3, p7, u[6]) + p5;
        u[6] = u[6] + p7;
        u[7] = fma(sk4, dp, d0) + p7;
    };

    // gather waves: compute g for one row held in v, write ring[buf][idx]
    auto GROW = [&](float2 v, int buf, int idx) {
        float x0 = __shfl(v.x, 0, 64);
        float a0 = __shfl(v.x, la.x >> 1, 64), b0 = __shfl(v.y, la.x >> 1, 64);
        float a1 = __shfl(v.x, la.y >> 1, 64), b1 = __shfl(v.y, la.y >> 1, 64);
        float a2 = __shfl(v.x, la.z >> 1, 64), b2 = __shfl(v.y, la.z >> 1, 64);
        float a3 = __shfl(v.x, la.w >> 1, 64), b3 = __shfl(v.y, la.w >> 1, 64);
        float g0 = (la.x & 1) ? b0 : a0;
        float g1 = (la.y & 1) ? b1 : a1;
        float g2 = (la.z & 1) ? b2 : a2;
        float g3 = (la.w & 1) ? b3 : a3;
        float o0 = (4 * lane + 0 < tl) ? __expf(g0 - x0) : 0.f;
        float o1 = (4 * lane + 1 < tl) ? __expf(g1 - x0) : 0.f;
        float o2 = (4 * lane + 2 < tl) ? __expf(g2 - x0) : 0.f;
        float o3 = (4 * lane + 3 < tl) ? __expf(g3 - x0) : 0.f;
        uint2 w;
        w.x = f32_to_bf16_rne(o0) | (f32_to_bf16_rne(o1) << 16);
        w.y = f32_to_bf16_rne(o2) | (f32_to_bf16_rne(o3) << 16);
        ring[buf][idx][lane] = w;
    };

    // wv2: z_t - x0_t for one row in v; accumulate if keep
    auto ZROW = [&](float2 v, bool keep) {
        float x0 = __shfl(v.x, 0, 64);
        float s = __expf(v.x - x0) + __expf(v.y - x0);
        #pragma unroll
        for (int off = 32; off >= 1; off >>= 1) s += __shfl_xor(s, off, 64);
        if (keep) zs += (double)__logf(s);
    };

    const int h16 = (wv == 3) ? 16 : 0;   // gather-wave half offset

    if (dir == 0) {
        // ---------------- forward: rows 0..m-1 (row 0 = init) -------------
        #pragma unroll
        for (int j = 0; j < 9; ++j) u[j] = 0.0;
        const int nrows = m;
        const int nch = (nrows + 31) >> 5;
        for (int it = 0; it <= nch; ++it) {
            if ((wv == 1 || wv == 3) && it < nch) {   // produce half-chunk
                int base = (it << 5) + h16, buf = it & 1;
                float2 vr[16];
                #pragma unroll
                for (int j = 0; j < 16; ++j)
                    vr[j] = rowp[(size_t)(base + j) * 64 + lane];
                #pragma unroll
                for (int j = 0; j < 16; ++j) GROW(vr[j], buf, h16 + j);
            }
            if (wv == 2 && it < nch) {       // z for chunk it's rows
                int base = it << 5;
                #pragma unroll
                for (int h = 0; h < 2; ++h) {
                    float2 vr[16];
                    #pragma unroll
                    for (int j = 0; j < 16; ++j)
                        vr[j] = rowp[(size_t)(base + h * 16 + j) * 64 + lane];
                    #pragma unroll
                    for (int j = 0; j < 16; ++j)
                        ZROW(vr[j], base + h * 16 + j < nrows);
                }
            }
            if (wv == 0 && it >= 1) {        // consume chunk it-1
                int c = it - 1;
                int buf = c & 1;
                uint2 rr[4];
                #pragma unroll
                for (int j = 0; j < 4; ++j) rr[j] = ring[buf][j][lane];
                if (c == 0) {                // init row + 31 steps
                    if (lane == 0) {
                        u[0] = 1.0;
                        u[1] = (double)__uint_as_float(rr[0].x << 16);
                    }
                    rr[0] = ring[buf][4][lane];
                    #pragma unroll
                    for (int i = 1; i < 32; ++i) {
                        uint2 q = rr[i & 3];
                        if (i + 4 < 32) rr[i & 3] = ring[buf][i + 4][lane];
                        FSTEP_Q(q);
                    }
                } else if (((c + 1) << 5) <= nrows) {   // full chunk
                    #pragma unroll
                    for (int i = 0; i < 32; ++i) {
                        uint2 q = rr[i & 3];
                        if (i + 4 < 32) rr[i & 3] = ring[buf][i + 4][lane];
                        FSTEP_Q(q);
                    }
                } else {                                 // tail chunk
                    int rem = nrows - (c << 5);
                    #pragma unroll
                    for (int i = 0; i < 32; ++i) {
                        if (i < rem) {
                            uint2 q = rr[i & 3];
                            if (i + 4 < 32) rr[i & 3] = ring[buf][i + 4][lane];
                            FSTEP_Q(q);
                        }
                    }
                }
                if (c & 1) RESCALE();        // <=64-step spacing
            }
            __syncthreads();
        }
        if (wv == 0) {
            RESCALE();                       // normalize before junction
            double* outv = fwdv + (size_t)b * 520;
            #pragma unroll
            for (int j = 0; j < 8; ++j) outv[8 * lane + j] = u[j];
            if (lane == 63) outv[512] = u[8];
            if (lane == 0)  Kf[b] = K;
        }
    } else {
        // ---------------- backward: k=0..nb-1, row = len-1-k --------------
        const int nb = len - m;              // >= 32
        #pragma unroll
        for (int j = 0; j < 8; ++j) {
            int s = 8 * lane + j;
            u[j] = (s == 2 * tl || s == 2 * tl - 1) ? 1.0 : 0.0;
        }
        u[8] = (lane == 63 && L == 513) ? 1.0 : 0.0;   // slot 512 (lane 63)
        const int nrows = nb;
        const int nch = (nrows + 31) >> 5;
        for (int it = 0; it <= nch; ++it) {
            if ((wv == 1 || wv == 3) && it < nch) {
                int base = (it << 5) + h16, buf = it & 1;
                float2 vr[16];
                #pragma unroll
                for (int j = 0; j < 16; ++j)
                    vr[j] = rowp[(size_t)(len - 1 - (base + j)) * 64 + lane];
                #pragma unroll
                for (int j = 0; j < 16; ++j) GROW(vr[j], buf, h16 + j);
            }
            if (wv == 2 && it < nch) {
                int base = it << 5;
                #pragma unroll
                for (int h = 0; h < 2; ++h) {
                    float2 vr[16];
                    #pragma unroll
                    for (int j = 0; j < 16; ++j)
                        vr[j] = rowp[(size_t)(len - 1 - (base + h * 16 + j)) * 64 + lane];
                    #pragma unroll
                    for (int j = 0; j < 16; ++j)
                        ZROW(vr[j], base + h * 16 + j < nrows);
                }
            }
            if (wv == 0 && it >= 1) {
                int c = it - 1;
                int buf = c & 1;
                uint2 rr[4];
                #pragma unroll
                for (int j = 0; j < 4; ++j) rr[j] = ring[buf][j][lane];
                if (((c + 1) << 5) <= nrows) {    // full chunk
                    #pragma unroll
                    for (int i = 0; i < 32; ++i) {
                        uint2 q = rr[i & 3];
                        if (i + 4 < 32) rr[i & 3] = ring[buf][i + 4][lane];
                        BSTEP_Q(q);
                    }
                } else {                          // tail chunk
                    int rem = nrows - (c << 5);
                    #pragma unroll
                    for (int i = 0; i < 32; ++i) {
                        if (i < rem) {
                            uint2 q = rr[i & 3];
                            if (i + 4 < 32) rr[i & 3] = ring[buf][i + 4][lane];
                            BSTEP_Q(q);
                        }
                    }
                }
                if (c & 1) RESCALE();
            }
            __syncthreads();
        }
        if (wv == 0) {
            RESCALE();
            double* outv = bwdv + (size_t)b * 520;
            #pragma unroll
            for (int j = 0; j < 8; ++j) outv[8 * lane + j] = u[j];
            if (lane == 63) outv[512] = u[8];
            if (lane == 0)  Kb[b] = K;
        }
    }

    // -------- zs handoff (wv2 -> wv0), then inter-block rendezvous --------
    if (wv == 2 && lane == 0) zsh = zs;
    __syncthreads();
    if (wv != 0) return;                 // producers done (no barriers left)

    if (lane == 0) zpart[blk] = zsh;     // publish this half's zs
    __threadfence();
    int prev = 0;
    if (lane == 0)
        prev = __hip_atomic_fetch_add(&done[b], 1, __ATOMIC_ACQ_REL,
                                      __HIP_MEMORY_SCOPE_AGENT);
    prev = __shfl(prev, 0, 64);
    if (prev == 0) return;               // first arriver: exit immediately
    __threadfence();                     // acquire the other block's stores

    const double* f = fwdv + (size_t)b * 520;
    const double* w = bwdv + (size_t)b * 520;
    double c = 0.0;
    #pragma unroll
    for (int j = 0; j < 8; ++j)
        c = fma(f[8 * lane + j], w[8 * lane + j], c);
    if (lane == 63) c = fma(f[512], w[512], c);
    #pragma unroll
    for (int off = 32; off >= 1; off >>= 1) c += __shfl_xor(c, off, 64);

    if (lane == 0) {
        double zstot = zpart[2 * b] + zpart[2 * b + 1];
        double logp = log(c)
                    + (double)(Kf[b] + Kb[b]) * 0.6931471805599453 - zstot;
        double loss = -logp;
        if (!(loss < 1e10)) loss = 0.0;   // zero_infinity (+inf / NaN)
        if (loss < 0.0)     loss = 0.0;   // CTC loss >= 0: circuit breaker
        lossb[b] = (float)(loss / (double)tl);
        __threadfence();
        int pg = __hip_atomic_fetch_add(gdone, 1, __ATOMIC_ACQ_REL,
                                        __HIP_MEMORY_SCOPE_AGENT);
        if (pg == B - 1) {                // last batch: deterministic mean
            __threadfence();
            float ssum = 0.0f;
            for (int i = 0; i < B; ++i) ssum += lossb[i];
            out[0] = ssum / (float)B;
        }
    }
}

// ======================= PATH B (fallback: proven round-3) ==================
constexpr int SPL  = 9;
constexpr int RING = 32;

__global__ void ctc_reduce_kernel(const float* __restrict__ ls,
                                  float* __restrict__ out, int B)
{
    if (blockIdx.x == 0 && threadIdx.x == 0) {
        float s = 0.0f;
        for (int i = 0; i < B; ++i) s += ls[i];
        out[0] = s / (float)B;
    }
}

__global__ __launch_bounds__(256) void softmax_z_kernel(
    const float* __restrict__ pred, float* __restrict__ z, int nrows)
{
    int w    = blockIdx.x * 4 + (threadIdx.x >> 6);
    int lane = threadIdx.x & 63;
    if (w >= nrows) return;
    const float2* p = (const float2*)pred;
    float2 v = p[(size_t)w * 64 + lane];
    float s = __expf(v.x) + __expf(v.y);
    #pragma unroll
    for (int off = 32; off >= 1; off >>= 1) s += __shfl_xor(s, off, 64);
    if (lane == 0) z[w] = __logf(s);
}

__device__ __forceinline__ void ctc_step_fb(
    const float* __restrict__ rowbase, const int* __restrict__ goff,
    const double* __restrict__ skd, double (&u)[SPL], int lane)
{
    float gf[SPL];
    #pragma unroll
    for (int j = 0; j < SPL; ++j)
        gf[j] = *(const float*)((const char*)rowbase + goff[j]);
    double um1 = __shfl_up(u[8], 1, 64);
    double um2 = __shfl_up(u[7], 1, 64);
    if (lane == 0) { um1 = 0.0; um2 = 0.0; }
    #pragma unroll
    for (int jj = 0; jj < SPL; ++jj) {
        int j = SPL - 1 - jj;
        double a2 = (j >= 1) ? u[j - 1] : um1;
        double a3 = (j >= 2) ? u[j - 2] : ((j == 1) ? um1 : um2);
        double t  = fma(skd[j], a3, a2) + u[j];
        u[j] = t * (double)gf[j];
    }
}

__device__ __forceinline__ void ctc_rescale_fb(double (&u)[SPL], int& K)
{
    double m = u[0];
    #pragma unroll
    for (int j = 1; j < SPL; ++j) m = fmax(m, u[j]);
    #pragma unroll
    for (int off = 32; off >= 1; off >>= 1) m = fmax(m, __shfl_xor(m, off, 64));
    if (m > 0.0) {
        int e = (__double2hiint(m) >> 20) & 0x7ff;
        int k = e - 1023;
        #pragma unroll
        for (int j = 0; j < SPL; ++j) u[j] = ldexp(u[j], -k);
        K += k;
    }
}

__global__ __launch_bounds__(64) void ctc_scan_kernel(
    const float* __restrict__ pred, const int* __restrict__ pred_len,
    const int* __restrict__ gt, const int* __restrict__ gt_len,
    const float* __restrict__ z, float* __restrict__ loss_out, int T, int S)
{
    const int b    = blockIdx.x;
    const int lane = threadIdx.x;
    const int len  = pred_len[b];
    const int tl   = gt_len[b];
    const int L    = 2 * tl + 1;

    __shared__ float ring[RING][V];
    __shared__ int   gts[512];

    for (int i = lane; i < S; i += 64) gts[i] = gt[b * S + i];
    __syncthreads();

    int    goff[SPL];
    double skd[SPL];
    #pragma unroll
    for (int j = 0; j < SPL; ++j) {
        int s = SPL * lane + j;
        int e = 0, ep = 0;
        if (s < L && (s & 1)) e = gts[s >> 1];
        if (s >= 2 && s < L && (s & 1)) ep = gts[(s - 2) >> 1];
        goff[j] = e * 4;
        skd[j]  = (s >= 2 && s < L && e != 0 && e != ep) ? 1.0 : 0.0;
    }

    const float2* rowp = (const float2*)(pred + (size_t)b * T * V);
    float2 raw[16];

    #pragma unroll
    for (int i = 0; i < 16; ++i) raw[i] = rowp[(size_t)i * 64 + lane];
    #pragma unroll
    for (int i = 0; i < 16; ++i) {
        float2 w; w.x = __expf(raw[i].x); w.y = __expf(raw[i].y);
        *(float2*)&ring[i][2 * lane] = w;
    }
    #pragma unroll
    for (int i = 0; i < 16; ++i) raw[i] = rowp[(size_t)(16 + i) * 64 + lane];
    #pragma unroll
    for (int i = 0; i < 16; ++i) {
        float2 w; w.x = __expf(raw[i].x); w.y = __expf(raw[i].y);
        *(float2*)&ring[16 + i][2 * lane] = w;
    }
    #pragma unroll
    for (int i = 0; i < 16; ++i) {
        int r = 32 + i; if (r > T - 1) r = T - 1;
        raw[i] = rowp[(size_t)r * 64 + lane];
    }

    double u[SPL];
    #pragma unroll
    for (int j = 0; j < SPL; ++j) {
        int s = SPL * lane + j;
        float w0 = *(const float*)((const char*)&ring[0][0] + goff[j]);
        u[j] = (s < 2) ? (double)w0 : 0.0;
    }
    int K = 0;

    for (int t = 1; t < 16 && t < len; ++t)
        ctc_step_fb(&ring[t & (RING - 1)][0], goff, skd, u, lane);
    ctc_rescale_fb(u, K);

    int tb = 16;
    for (; tb + 16 <= len; tb += 16) {
        #pragma unroll
        for (int i = 0; i < 16; ++i) {
            float2 w; w.x = __expf(raw[i].x); w.y = __expf(raw[i].y);
            *(float2*)&ring[(tb + 16 + i) & (RING - 1)][2 * lane] = w;
        }
        #pragma unroll
        for (int i = 0; i < 16; ++i) {
            int r = tb + 32 + i; if (r > T - 1) r = T - 1;
            raw[i] = rowp[(size_t)r * 64 + lane];
        }
        #pragma unroll
        for (int i = 0; i < 16; ++i)
            ctc_step_fb(&ring[(tb + i) & (RING - 1)][0], goff, skd, u, lane);
        ctc_rescale_fb(u, K);
    }

    for (int t = tb; t < len; ++t)
        ctc_step_fb(&ring[t & (RING - 1)][0], goff, skd, u, lane);

    double contrib = 0.0;
    #pragma unroll
    for (int j = 0; j < SPL; ++j) {
        int s = SPL * lane + j;
        if (s == L - 1 || s == L - 2) contrib += u[j];
    }
    #pragma unroll
    for (int off = 32; off >= 1; off >>= 1)
        contrib += __shfl_xor(contrib, off, 64);

    double zsum = 0.0;
    for (int t = lane; t < len; t += 64) zsum += (double)z[b * T + t];
    #pragma unroll
    for (int off = 32; off >= 1; off >>= 1)
        zsum += __shfl_xor(zsum, off, 64);

    if (lane == 0) {
        double lg    = log(contrib);
        double alpha = lg + (double)K * 0.6931471805599453 - zsum;
        double loss  = -alpha;
        if (!(loss < 1e10)) loss = 0.0;
        loss_out[b] = (float)(loss / (double)tl);
    }
}

// ======================= host =======================
extern "C" void kernel_launch(void* const* d_in, const int* in_sizes, int n_in,
                              void* d_out, int out_size, void* d_ws, size_t ws_size,
                              hipStream_t stream) {
    const float* pred = (const float*)d_in[0];   // [B, T, V] fp32
    const int*   plen = (const int*)d_in[1];     // [B]
    const int*   gts  = (const int*)d_in[2];     // [B, S]
    const int*   glen = (const int*)d_in[3];     // [B]

    const int B = in_sizes[1];
    const int S = in_sizes[2] / B;
    const int T = in_sizes[0] / (B * V);
    const size_t BT = (size_t)B * T;

    float* out = (float*)d_out;
    char*  ws  = (char*)d_ws;

    // fast-path workspace layout (tiny now: no g/z intermediates)
    size_t off_fl = 0;                               // done[64]@0 gdone@256 lossb@512
    size_t off_zp = 1024;                            // zpart: 2B doubles
    size_t off_fw = 2048;
    size_t off_bw = off_fw + (size_t)B * 520 * 8;
    size_t off_kf = off_bw + (size_t)B * 520 * 8;
    size_t off_kb = off_kf + (size_t)B * 4;
    size_t need   = off_kb + (size_t)B * 4;

    // T >= 128 (=> len >= 64 => m,nb >= 32) required by 32-row chunking
    bool fast_ok = (ws_size >= need) && (S == 256) &&
                   (T >= 128) && (B >= 1) && (B <= 64);

    if (fast_ok) {
        int*    flags = (int*)(ws + off_fl);
        int*    done  = flags;
        int*    gdone = flags + 64;
        float*  lossb = (float*)(ws + off_fl + 512);
        double* zp    = (double*)(ws + off_zp);
        double* fw    = (double*)(ws + off_fw);
        double* bw    = (double*)(ws + off_bw);
        int*    kf    = (int*)(ws + off_kf);
        int*    kb    = (int*)(ws + off_kb);

        hipMemsetAsync(ws + off_fl, 0, 512, stream);   // done + gdone
        ctc_fused_bi<<<2 * B, 256, 0, stream>>>(pred, plen, gts, glen,
                                                fw, bw, kf, kb, zp,
                                                done, gdone, lossb, out,
                                                T, S, B);
    } else {
        float* zbuf = (float*)ws;                 // B*T
        float* lb   = zbuf + BT;                  // B
        int nrows = B * T;
        softmax_z_kernel<<<(nrows + 3) / 4, 256, 0, stream>>>(pred, zbuf, nrows);
        ctc_scan_kernel<<<B, 64, 0, stream>>>(pred, plen, gts, glen, zbuf, lb, T, S);
        ctc_reduce_kernel<<<1, 64, 0, stream>>>(lb, out, B);
    }
}